// Round 13
// baseline (175.846 us; speedup 1.0000x reference)
//
#include <hip/hip_runtime.h>
#include <math.h>

#define DM 512
#define NN 512
#define SCALE 651.8986469044033f   // 4096/(2*pi), rounds to same f32 as reference
#define MAGIC 12582912.0f          // 1.5 * 2^23: fma+magic => RNE integer in low mantissa
#define NLUT 5                     // tokens 0..4 -> LDS LUT; tokens 5..7 -> v_sin/v_cos

typedef __attribute__((ext_vector_type(8))) short short8v;
typedef __attribute__((ext_vector_type(4))) float f32x4;

__device__ __forceinline__ unsigned bf16rne(float f) {
    unsigned u = __float_as_uint(f);
    return (u + 0x7fffu + ((u >> 16) & 1u)) >> 16;
}

// Fragment address for MFMA 16x16x32 bf16 operands, u32 granularity.
// Operand rows (A: t, B: d) tile by 16; k = 2n + {0=cos,1=sin}.
// lane l = (row&15) + 16*q, q = (n>>2)&3; u32 slot s = n&3; kk = n>>4.
__device__ __forceinline__ int frag_idx(int row, int n) {
    int rt = row >> 4, m = row & 15;
    int kk = n >> 4, q = (n >> 2) & 3, s = n & 3;
    return ((rt * 32 + kk) * 64 + m + 16 * q) * 4 + s;
}

// ---------------------------------------------------------------------------
// kprep: 128 blocks.
//  mode 0 (64 tiles): LDS-transpose W,B,AC,AS -> packAB[d][n] float4
//                     {SCALE/(1+|W|), B*SCALE+MAGIC, attn_cos, attn_sin}
//  mode 1 (64 tiles): pack PC/PS into the MFMA B-fragment layout (bfrag).
// ---------------------------------------------------------------------------
__global__ __launch_bounds__(256) void kprep(
    const float* __restrict__ W, const float* __restrict__ B,
    const float* __restrict__ AC, const float* __restrict__ AS,
    const float* __restrict__ PC, const float* __restrict__ PS,
    float4* __restrict__ packAB, unsigned* __restrict__ bfrag)
{
    __shared__ float4 tile4[64][65];
    const int tid = threadIdx.x;
    const int tx = tid & 63, ty = tid >> 6;
    const int mode = blockIdx.x >> 6;
    const int tl = blockIdx.x & 63;
    const int r0 = (tl >> 3) * 64;
    const int c0 = (tl & 7) * 64;

    if (mode == 0) {
#pragma unroll
        for (int p = 0; p < 16; ++p) {
            int r = p * 4 + ty;
            int src = (r0 + r) * DM + c0 + tx;   // row = n, col = d
            float w = W[src], b = B[src];
            float iw = 1.0f + fabsf(w);
            tile4[r][tx] = make_float4(SCALE / iw, fmaf(b, SCALE, MAGIC),
                                       AC[src], AS[src]);
        }
        __syncthreads();
#pragma unroll
        for (int p = 0; p < 16; ++p) {
            int c = p * 4 + ty;
            packAB[(c0 + c) * NN + r0 + tx] = tile4[tx][c];
        }
    } else {
        // PC/PS are [d][n]: row = d, col = n -> B-fragment layout
#pragma unroll
        for (int p = 0; p < 16; ++p) {
            int r = p * 4 + ty;
            int d = r0 + r, n = c0 + tx;
            int src = d * NN + n;
            bfrag[frag_idx(d, n)] = bf16rne(PC[src]) | (bf16rne(PS[src]) << 16);
        }
    }
}

// ---------------------------------------------------------------------------
// kmain: intra-wave hybrid. Block = 512 thr = 8 waves, ALL IDENTICAL; block
// owns (8 tok)x(64 n); wave wv owns d-slice [wv*64,+64); lane = neuron.
// Per d-iter: tokens 0..NLUT-1 via LDS-LUT gather, tokens NLUT..7 via
// v_sin/v_cos — gathers issue FIRST, trans VALU work runs while they're in
// flight, unpacks come last: latency hiding is per-wave ILP (r12 showed
// cross-wave overlap fails: VALU 46% + LDS 53% ~= 100%, perfectly serial).
// Both paths share ONE quantization: f = fma(x*invc)+bcMagic;
// LUT: bits(f)&4095;  trans: J = f-MAGIC (exact int), ph = fract(J/4096) rev.
// ---------------------------------------------------------------------------
__global__ __launch_bounds__(512, 8) void kmain(
    const float* __restrict__ x,
    const float* __restrict__ sinT, const float* __restrict__ cosT,
    const float4* __restrict__ packAB,
    unsigned* __restrict__ afrag)
{
    __shared__ unsigned lut[4096];   // 16 KB: sin bf16 lo | cos bf16 hi
    __shared__ float xT[512][8];     // 16 KB: x-tile transposed
    __shared__ float2 accL[8][64];   // 4 KB accumulator

    const int tid  = threadIdx.x;
    const int bid  = blockIdx.x;     // 1024 = 128 tiles * 8 ng
    const int tile = bid >> 3, ng = bid & 7;
    const int lane = tid & 63;
    const int wv   = __builtin_amdgcn_readfirstlane(tid >> 6);
    const int t0   = tile * 8;

#pragma unroll
    for (int j = 0; j < 8; ++j) {
        int k = tid + j * 512;
        lut[k] = bf16rne(sinT[k]) | (bf16rne(cosT[k]) << 16);
    }
    {
        const int tt = tid & 7, dr = tid >> 3;
#pragma unroll
        for (int c = 0; c < 8; ++c) {
            int d = c * 64 + dr;
            xT[d][tt] = x[(t0 + tt) * DM + d];
        }
    }
    ((float2*)accL)[tid] = make_float2(0.f, 0.f);
    __syncthreads();

    float accC[8], accS[8];
#pragma unroll
    for (int t = 0; t < 8; ++t) { accC[t] = 0.f; accS[t] = 0.f; }

    const float4* pAB = packAB + (wv * 64) * NN + ng * 64 + lane;

#pragma unroll 2
    for (int i = 0; i < 64; ++i) {
        float4 a = pAB[i * NN];      // {invc, bcMagic, ac, as}
        const float4* xr = (const float4*)&xT[wv * 64 + i][0];
        float4 xq0 = xr[0], xq1 = xr[1];
        float xv[8] = {xq0.x, xq0.y, xq0.z, xq0.w, xq1.x, xq1.y, xq1.z, xq1.w};

        float f[8];
#pragma unroll
        for (int t = 0; t < 8; ++t) f[t] = fmaf(xv[t], a.x, a.y);

        // 1) issue the LUT gathers (non-blocking; lgkmcnt counted)
        unsigned u[NLUT];
#pragma unroll
        for (int t = 0; t < NLUT; ++t) u[t] = lut[__float_as_uint(f[t]) & 4095u];

        // 2) trans tokens: pure VALU/trans work while gathers are in flight
#pragma unroll
        for (int t = NLUT; t < 8; ++t) {
            float J  = f[t] - MAGIC;                   // RNE(theta*SCALE), exact
            float ph = __builtin_amdgcn_fractf(J * (1.0f / 4096.0f));
            accC[t] = fmaf(__builtin_amdgcn_cosf(ph), a.z, accC[t]);
            accS[t] = fmaf(__builtin_amdgcn_sinf(ph), a.w, accS[t]);
        }

        // 3) consume gather results
#pragma unroll
        for (int t = 0; t < NLUT; ++t) {
            accC[t] = fmaf(__uint_as_float(u[t] & 0xffff0000u), a.z, accC[t]);
            accS[t] = fmaf(__uint_as_float(u[t] << 16),         a.w, accS[t]);
        }
    }

#pragma unroll
    for (int t = 0; t < 8; ++t) {
        atomicAdd(&accL[t][lane].x, accC[t]);          // ds_add_f32
        atomicAdd(&accL[t][lane].y, accS[t]);
    }
    __syncthreads();
    {
        int t = tid >> 6, n64 = tid & 63;
        float2 v = accL[t][n64];
        afrag[frag_idx(t0 + t, ng * 64 + n64)] =
            bf16rne(v.x) | (bf16rne(v.y) << 16);
    }
}

// ---------------------------------------------------------------------------
// kproj: out = silu( A[1024 x 1024k] * B^T[512 x 1024k] ), k = {cos,sin}
// interleaved over n. Both operands pre-packed in MFMA fragment order:
// frag[rt][kk][lane] 16B -> every load is a fully-coalesced 1 KB dwordx4.
// Grid = 512 blocks x 256 thr (4 waves); wave owns one 16x16 out tile;
// no LDS, no barriers. D layout (m89-verified): col=lane&15, row=(lane>>4)*4+r.
// ---------------------------------------------------------------------------
__global__ __launch_bounds__(256) void kproj(
    const short8v* __restrict__ afrag, const short8v* __restrict__ bfrag,
    float* __restrict__ out)
{
    const int tid  = threadIdx.x;
    const int lane = tid & 63;
    const int w    = tid >> 6;
    const int tileIdx = blockIdx.x * 4 + w;      // 0..2047
    const int tt = tileIdx >> 5;                 // t-tile 0..63
    const int dt = tileIdx & 31;                 // d-tile 0..31

    const short8v* pa = afrag + tt * 32 * 64 + lane;   // + kk*64 per K-step
    const short8v* pb = bfrag + dt * 32 * 64 + lane;

    f32x4 acc = {0.f, 0.f, 0.f, 0.f};
#pragma unroll 8
    for (int kk = 0; kk < 32; ++kk) {
        short8v a = pa[kk * 64];
        short8v b = pb[kk * 64];
        acc = __builtin_amdgcn_mfma_f32_16x16x32_bf16(a, b, acc, 0, 0, 0);
    }
#pragma unroll
    for (int r = 0; r < 4; ++r) {
        int m = (lane >> 4) * 4 + r;
        float s = acc[r];
        float o = s / (1.f + __expf(-s));
        out[(tt * 16 + m) * DM + dt * 16 + (lane & 15)] = o;
    }
}

// ---------------------------------------------------------------------------
extern "C" void kernel_launch(void* const* d_in, const int* in_sizes, int n_in,
                              void* d_out, int out_size, void* d_ws, size_t ws_size,
                              hipStream_t stream)
{
    const float* x    = (const float*)d_in[0];
    const float* W    = (const float*)d_in[1];
    const float* B    = (const float*)d_in[2];
    const float* AC   = (const float*)d_in[3];
    const float* AS   = (const float*)d_in[4];
    const float* PC   = (const float*)d_in[5];
    const float* PS   = (const float*)d_in[6];
    const float* sinT = (const float*)d_in[7];
    const float* cosT = (const float*)d_in[8];
    float* out = (float*)d_out;

    char* ws = (char*)d_ws;
    float4*   packAB = (float4*)ws;                  // 4 MiB [d][n]
    unsigned* bfrag  = (unsigned*)(ws + (4u << 20)); // 1 MiB B-fragments
    unsigned* afrag  = (unsigned*)(ws + (6u << 20)); // 2 MiB A-fragments

    kprep<<<128, 256, 0, stream>>>(W, B, AC, AS, PC, PS, packAB, bfrag);
    kmain<<<1024, 512, 0, stream>>>(x, sinT, cosT, packAB, afrag);
    kproj<<<512, 256, 0, stream>>>((const short8v*)afrag, (const short8v*)bfrag, out);
}

// Round 14
// 173.879 us; speedup vs baseline: 1.0113x; 1.0113x over previous
//
#include <hip/hip_runtime.h>
#include <math.h>

#define DM 512
#define NN 512
#define SCALE 651.8986469044033f   // 4096/(2*pi), rounds to same f32 as reference
#define MAGIC 12582912.0f          // 1.5 * 2^23: fma+magic => RNE integer in low mantissa

typedef __attribute__((ext_vector_type(8))) short short8v;
typedef __attribute__((ext_vector_type(4))) float f32x4;

__device__ __forceinline__ unsigned bf16rne(float f) {
    unsigned u = __float_as_uint(f);
    return (u + 0x7fffu + ((u >> 16) & 1u)) >> 16;
}

// Fragment address for MFMA 16x16x32 bf16 operands, u32 granularity.
// Operand rows (A: t, B: d) tile by 16; k = 2n + {0=cos,1=sin}.
// lane l = (row&15) + 16*q, q = (n>>2)&3; u32 slot s = n&3; kk = n>>4.
__device__ __forceinline__ int frag_idx(int row, int n) {
    int rt = row >> 4, m = row & 15;
    int kk = n >> 4, q = (n >> 2) & 3, s = n & 3;
    return ((rt * 32 + kk) * 64 + m + 16 * q) * 4 + s;
}

// ---------------------------------------------------------------------------
// kprep: 128 blocks.
//  mode 0 (64 tiles): LDS-transpose W,B,AC,AS -> packAB[d][n] float4
//                     {SCALE/(1+|W|), B*SCALE+MAGIC, attn_cos, attn_sin}
//  mode 1 (64 tiles): pack PC/PS into the MFMA B-fragment layout (bfrag).
// ---------------------------------------------------------------------------
__global__ __launch_bounds__(256) void kprep(
    const float* __restrict__ W, const float* __restrict__ B,
    const float* __restrict__ AC, const float* __restrict__ AS,
    const float* __restrict__ PC, const float* __restrict__ PS,
    float4* __restrict__ packAB, unsigned* __restrict__ bfrag)
{
    __shared__ float4 tile4[64][65];
    const int tid = threadIdx.x;
    const int tx = tid & 63, ty = tid >> 6;
    const int mode = blockIdx.x >> 6;
    const int tl = blockIdx.x & 63;
    const int r0 = (tl >> 3) * 64;
    const int c0 = (tl & 7) * 64;

    if (mode == 0) {
#pragma unroll
        for (int p = 0; p < 16; ++p) {
            int r = p * 4 + ty;
            int src = (r0 + r) * DM + c0 + tx;   // row = n, col = d
            float w = W[src], b = B[src];
            float iw = 1.0f + fabsf(w);
            tile4[r][tx] = make_float4(SCALE / iw, fmaf(b, SCALE, MAGIC),
                                       AC[src], AS[src]);
        }
        __syncthreads();
#pragma unroll
        for (int p = 0; p < 16; ++p) {
            int c = p * 4 + ty;
            packAB[(c0 + c) * NN + r0 + tx] = tile4[tx][c];
        }
    } else {
        // PC/PS are [d][n]: row = d, col = n -> B-fragment layout
#pragma unroll
        for (int p = 0; p < 16; ++p) {
            int r = p * 4 + ty;
            int d = r0 + r, n = c0 + tx;
            int src = d * NN + n;
            bfrag[frag_idx(d, n)] = bf16rne(PC[src]) | (bf16rne(PS[src]) << 16);
        }
    }
}

// ---------------------------------------------------------------------------
// kmain: all-LUT with DEEP MLP. Block = 512 thr = 8 waves; block owns
// (8 tok)x(64 n); wave wv owns d-slice [wv*64,+64); lane = neuron.
// #pragma unroll 8 on the d-loop: compiler hoists 8 packAB b128 loads
// (8 KB VMEM in flight, hides ~200cy L2 latency) and interleaves 64
// independent LUT gathers/unpacks with counted lgkmcnt waits.
// (r13 lesson: v_sin/v_cos are 1/8-rate VALU-issue ops, NOT a parallel
// pipe — the trans path costs ~40 issue-cyc/elem vs LUT's ~18. All-LUT
// + stall removal is the only path below ~90 us.)
// ---------------------------------------------------------------------------
__global__ __launch_bounds__(512, 8) void kmain(
    const float* __restrict__ x,
    const float* __restrict__ sinT, const float* __restrict__ cosT,
    const float4* __restrict__ packAB,
    unsigned* __restrict__ afrag)
{
    __shared__ unsigned lut[4096];   // 16 KB: sin bf16 lo | cos bf16 hi
    __shared__ float xT[512][8];     // 16 KB: x-tile transposed
    __shared__ float2 accL[8][64];   // 4 KB accumulator

    const int tid  = threadIdx.x;
    const int bid  = blockIdx.x;     // 1024 = 128 tiles * 8 ng
    const int tile = bid >> 3, ng = bid & 7;
    const int lane = tid & 63;
    const int wv   = __builtin_amdgcn_readfirstlane(tid >> 6);
    const int t0   = tile * 8;

#pragma unroll
    for (int j = 0; j < 8; ++j) {
        int k = tid + j * 512;
        lut[k] = bf16rne(sinT[k]) | (bf16rne(cosT[k]) << 16);
    }
    {
        const int tt = tid & 7, dr = tid >> 3;
#pragma unroll
        for (int c = 0; c < 8; ++c) {
            int d = c * 64 + dr;
            xT[d][tt] = x[(t0 + tt) * DM + d];
        }
    }
    ((float2*)accL)[tid] = make_float2(0.f, 0.f);
    __syncthreads();

    float accC[8], accS[8];
#pragma unroll
    for (int t = 0; t < 8; ++t) { accC[t] = 0.f; accS[t] = 0.f; }

    const float4* pAB = packAB + (wv * 64) * NN + ng * 64 + lane;

#pragma unroll 8
    for (int i = 0; i < 64; ++i) {
        float4 a = pAB[i * NN];      // {invc, bcMagic, ac, as}
        const float4* xr = (const float4*)&xT[wv * 64 + i][0];
        float4 xq0 = xr[0], xq1 = xr[1];     // wave-uniform broadcasts

        unsigned u0 = lut[__float_as_uint(fmaf(xq0.x, a.x, a.y)) & 4095u];
        unsigned u1 = lut[__float_as_uint(fmaf(xq0.y, a.x, a.y)) & 4095u];
        unsigned u2 = lut[__float_as_uint(fmaf(xq0.z, a.x, a.y)) & 4095u];
        unsigned u3 = lut[__float_as_uint(fmaf(xq0.w, a.x, a.y)) & 4095u];
        unsigned u4 = lut[__float_as_uint(fmaf(xq1.x, a.x, a.y)) & 4095u];
        unsigned u5 = lut[__float_as_uint(fmaf(xq1.y, a.x, a.y)) & 4095u];
        unsigned u6 = lut[__float_as_uint(fmaf(xq1.z, a.x, a.y)) & 4095u];
        unsigned u7 = lut[__float_as_uint(fmaf(xq1.w, a.x, a.y)) & 4095u];

        accC[0] = fmaf(__uint_as_float(u0 & 0xffff0000u), a.z, accC[0]);
        accS[0] = fmaf(__uint_as_float(u0 << 16),         a.w, accS[0]);
        accC[1] = fmaf(__uint_as_float(u1 & 0xffff0000u), a.z, accC[1]);
        accS[1] = fmaf(__uint_as_float(u1 << 16),         a.w, accS[1]);
        accC[2] = fmaf(__uint_as_float(u2 & 0xffff0000u), a.z, accC[2]);
        accS[2] = fmaf(__uint_as_float(u2 << 16),         a.w, accS[2]);
        accC[3] = fmaf(__uint_as_float(u3 & 0xffff0000u), a.z, accC[3]);
        accS[3] = fmaf(__uint_as_float(u3 << 16),         a.w, accS[3]);
        accC[4] = fmaf(__uint_as_float(u4 & 0xffff0000u), a.z, accC[4]);
        accS[4] = fmaf(__uint_as_float(u4 << 16),         a.w, accS[4]);
        accC[5] = fmaf(__uint_as_float(u5 & 0xffff0000u), a.z, accC[5]);
        accS[5] = fmaf(__uint_as_float(u5 << 16),         a.w, accS[5]);
        accC[6] = fmaf(__uint_as_float(u6 & 0xffff0000u), a.z, accC[6]);
        accS[6] = fmaf(__uint_as_float(u6 << 16),         a.w, accS[6]);
        accC[7] = fmaf(__uint_as_float(u7 & 0xffff0000u), a.z, accC[7]);
        accS[7] = fmaf(__uint_as_float(u7 << 16),         a.w, accS[7]);
    }

#pragma unroll
    for (int t = 0; t < 8; ++t) {
        atomicAdd(&accL[t][lane].x, accC[t]);          // ds_add_f32
        atomicAdd(&accL[t][lane].y, accS[t]);
    }
    __syncthreads();
    {
        int t = tid >> 6, n64 = tid & 63;
        float2 v = accL[t][n64];
        afrag[frag_idx(t0 + t, ng * 64 + n64)] =
            bf16rne(v.x) | (bf16rne(v.y) << 16);
    }
}

// ---------------------------------------------------------------------------
// kproj: out = silu( A[1024 x 1024k] * B^T[512 x 1024k] ), k = {cos,sin}
// interleaved over n. Both operands pre-packed in MFMA fragment order:
// frag[rt][kk][lane] 16B -> every load is a fully-coalesced 1 KB dwordx4.
// Grid = 512 blocks x 256 thr (4 waves); wave owns one 16x16 out tile;
// no LDS, no barriers. D layout (m89-verified): col=lane&15, row=(lane>>4)*4+r.
// ---------------------------------------------------------------------------
__global__ __launch_bounds__(256) void kproj(
    const short8v* __restrict__ afrag, const short8v* __restrict__ bfrag,
    float* __restrict__ out)
{
    const int tid  = threadIdx.x;
    const int lane = tid & 63;
    const int w    = tid >> 6;
    const int tileIdx = blockIdx.x * 4 + w;      // 0..2047
    const int tt = tileIdx >> 5;                 // t-tile 0..63
    const int dt = tileIdx & 31;                 // d-tile 0..31

    const short8v* pa = afrag + tt * 32 * 64 + lane;   // + kk*64 per K-step
    const short8v* pb = bfrag + dt * 32 * 64 + lane;

    f32x4 acc = {0.f, 0.f, 0.f, 0.f};
#pragma unroll 8
    for (int kk = 0; kk < 32; ++kk) {
        short8v a = pa[kk * 64];
        short8v b = pb[kk * 64];
        acc = __builtin_amdgcn_mfma_f32_16x16x32_bf16(a, b, acc, 0, 0, 0);
    }
#pragma unroll
    for (int r = 0; r < 4; ++r) {
        int m = (lane >> 4) * 4 + r;
        float s = acc[r];
        float o = s / (1.f + __expf(-s));
        out[(tt * 16 + m) * DM + dt * 16 + (lane & 15)] = o;
    }
}

// ---------------------------------------------------------------------------
extern "C" void kernel_launch(void* const* d_in, const int* in_sizes, int n_in,
                              void* d_out, int out_size, void* d_ws, size_t ws_size,
                              hipStream_t stream)
{
    const float* x    = (const float*)d_in[0];
    const float* W    = (const float*)d_in[1];
    const float* B    = (const float*)d_in[2];
    const float* AC   = (const float*)d_in[3];
    const float* AS   = (const float*)d_in[4];
    const float* PC   = (const float*)d_in[5];
    const float* PS   = (const float*)d_in[6];
    const float* sinT = (const float*)d_in[7];
    const float* cosT = (const float*)d_in[8];
    float* out = (float*)d_out;

    char* ws = (char*)d_ws;
    float4*   packAB = (float4*)ws;                  // 4 MiB [d][n]
    unsigned* bfrag  = (unsigned*)(ws + (4u << 20)); // 1 MiB B-fragments
    unsigned* afrag  = (unsigned*)(ws + (6u << 20)); // 2 MiB A-fragments

    kprep<<<128, 256, 0, stream>>>(W, B, AC, AS, PC, PS, packAB, bfrag);
    kmain<<<1024, 512, 0, stream>>>(x, sinT, cosT, packAB, afrag);
    kproj<<<512, 256, 0, stream>>>((const short8v*)afrag, (const short8v*)bfrag, out);
}